// Round 2
// baseline (292.629 us; speedup 1.0000x reference)
//
#include <hip/hip_runtime.h>

#define HW 128
#define TW 32
#define TH 8
#define HALO_W 34
#define NH 340          // 34 x 10 halo tile
#define CPB 4           // channels per round
#define ROUNDS 16       // 64 / CPB

__device__ __forceinline__ float lrelu(float x) { return x > 0.f ? x : 0.1f * x; }

// ---------------- prep: att-scaled depthwise kernels -> ws ----------------
__global__ __launch_bounds__(64) void dgfem_prep(
    const float* __restrict__ v, const float* __restrict__ ca_w1,
    const float* __restrict__ ca_w2, const float* __restrict__ k_w1,
    const float* __restrict__ k_w2, float* __restrict__ kernArr)
{
    const int b = blockIdx.x;
    const int t = threadIdx.x;           // 64 threads
    __shared__ float vb[64], t1[8], att[64], t2[64];

    vb[t] = v[b * 64 + t];
    __syncthreads();

    if (t < 8) {
        float s = 0.f;
        for (int j = 0; j < 64; ++j) s += vb[j] * ca_w1[t * 64 + j];
        t1[t] = lrelu(s);
    }
    {
        float s = 0.f;
        for (int j = 0; j < 64; ++j) s += vb[j] * k_w1[t * 64 + j];
        t2[t] = lrelu(s);
    }
    __syncthreads();
    {
        float s = 0.f;
        for (int i = 0; i < 8; ++i) s += t1[i] * ca_w2[t * 8 + i];
        att[t] = 1.f / (1.f + expf(-s));
    }
    __syncthreads();
    // 576 rows of k_w2; fold att[c] into kernel (conv(x*a,k) == conv(x,a*k))
    for (int r = t; r < 576; r += 64) {
        float s = 0.f;
        for (int j = 0; j < 64; ++j) s += t2[j] * k_w2[r * 64 + j];
        kernArr[b * 576 + r] = s * att[r / 9];
    }
}

// -------- fused: depthwise 3x3 + lrelu + 1x1 conv + bias (4 ch / round) --------
__global__ __launch_bounds__(256) void dgfem_main(
    const float* __restrict__ x0, const float* __restrict__ kernArr,
    const float* __restrict__ conv_w, const float* __restrict__ conv_b,
    float* __restrict__ out)
{
    const int t  = threadIdx.x;          // 256
    const int b  = blockIdx.z;
    const int tx = blockIdx.x * TW;
    const int ty = blockIdx.y * TH;
    const int px = t & (TW - 1);
    const int py = t >> 5;

    __shared__ float wT[4096];           // wT[c*64+o] = conv_w[o*64+c]
    __shared__ float bias[64];
    __shared__ float xs[2][CPB][NH];
    __shared__ float ks[2][40];          // CPB*9 = 36, padded

    for (int i = t; i < 4096; i += 256)
        wT[(i & 63) * 64 + (i >> 6)] = conv_w[i];   // coalesced read, transposed scatter
    if (t < 64) bias[t] = conv_b[t];

    // ---- channel-invariant staging geometry (computed ONCE) ----
    const int  ly0 = t / HALO_W, lx0 = t - ly0 * HALO_W;
    const int  gx0 = tx + lx0 - 1, gy0 = ty + ly0 - 1;
    const bool in0 = ((unsigned)gx0 < HW) && ((unsigned)gy0 < HW);
    const int  off0 = in0 ? (gy0 * HW + gx0) : 0;
    const int  i1  = t + 256;
    const bool has1 = (i1 < NH);
    const int  ly1 = i1 / HALO_W, lx1 = i1 - ly1 * HALO_W;
    const int  gx1 = tx + lx1 - 1, gy1 = ty + ly1 - 1;
    const bool in1 = has1 && ((unsigned)gx1 < HW) && ((unsigned)gy1 < HW);
    const int  off1 = in1 ? (gy1 * HW + gx1) : 0;

    const size_t bbase = (size_t)b * 64 * HW * HW;
    const float* xb = x0 + bbase;

    float acc[64];
    #pragma unroll
    for (int o = 0; o < 64; ++o) acc[o] = 0.f;

    // ---- stage round 0 into buffer 0 ----
    {
        #pragma unroll
        for (int cc = 0; cc < CPB; ++cc) {
            const float* xc = xb + cc * (HW * HW);
            float a0 = xc[off0];
            xs[0][cc][t] = in0 ? a0 : 0.f;
            if (has1) { float a1 = xc[off1]; xs[0][cc][i1] = in1 ? a1 : 0.f; }
        }
        if (t < CPB * 9) ks[0][t] = kernArr[(size_t)(b * 64) * 9 + t];
    }
    __syncthreads();

    for (int r = 0; r < ROUNDS; ++r) {
        const int cur = r & 1;
        const bool pf = (r + 1 < ROUNDS);

        // ---- issue next round's loads EARLY (into registers) ----
        float p0[CPB], p1[CPB], kv = 0.f;
        if (pf) {
            const float* xn = xb + (size_t)(r + 1) * CPB * (HW * HW);
            #pragma unroll
            for (int cc = 0; cc < CPB; ++cc) {
                const float* xc = xn + cc * (HW * HW);
                p0[cc] = xc[off0];
                p1[cc] = has1 ? xc[off1] : 0.f;
            }
            if (t < CPB * 9) kv = kernArr[(size_t)(b * 64 + (r + 1) * CPB) * 9 + t];
        }

        // ---- compute current round (hides the loads above) ----
        #pragma unroll
        for (int cc = 0; cc < CPB; ++cc) {
            const float* kp = &ks[cur][cc * 9];
            const float* xp = &xs[cur][cc][py * HALO_W + px];
            float yv = 0.f;
            #pragma unroll
            for (int dy = 0; dy < 3; ++dy)
                #pragma unroll
                for (int dx = 0; dx < 3; ++dx)
                    yv += kp[dy * 3 + dx] * xp[dy * HALO_W + dx];
            yv = lrelu(yv);

            const float4* w4 = (const float4*)&wT[(r * CPB + cc) * 64];
            #pragma unroll
            for (int o4 = 0; o4 < 16; ++o4) {
                float4 wv = w4[o4];
                acc[o4 * 4 + 0] += wv.x * yv;
                acc[o4 * 4 + 1] += wv.y * yv;
                acc[o4 * 4 + 2] += wv.z * yv;
                acc[o4 * 4 + 3] += wv.w * yv;
            }
        }

        // ---- write prefetched values to the other buffer, then ONE barrier ----
        if (pf) {
            #pragma unroll
            for (int cc = 0; cc < CPB; ++cc) {
                xs[cur ^ 1][cc][t] = in0 ? p0[cc] : 0.f;
                if (has1) xs[cur ^ 1][cc][i1] = in1 ? p1[cc] : 0.f;
            }
            if (t < CPB * 9) ks[cur ^ 1][t] = kv;
        }
        __syncthreads();
    }

    float* op = out + bbase + (size_t)(ty + py) * HW + (tx + px);
    #pragma unroll
    for (int o = 0; o < 64; ++o)
        op[(size_t)o * (HW * HW)] = acc[o] + bias[o];
}

extern "C" void kernel_launch(void* const* d_in, const int* in_sizes, int n_in,
                              void* d_out, int out_size, void* d_ws, size_t ws_size,
                              hipStream_t stream) {
    const float* x0     = (const float*)d_in[0];
    const float* v      = (const float*)d_in[1];
    const float* ca_w1  = (const float*)d_in[2];
    const float* ca_w2  = (const float*)d_in[3];
    const float* k_w1   = (const float*)d_in[4];
    const float* k_w2   = (const float*)d_in[5];
    const float* conv_w = (const float*)d_in[6];
    const float* conv_b = (const float*)d_in[7];
    float* kernArr = (float*)d_ws;       // 32*64*9 floats = 73728 B
    float* outp    = (float*)d_out;

    dgfem_prep<<<dim3(32), dim3(64), 0, stream>>>(v, ca_w1, ca_w2, k_w1, k_w2, kernArr);
    dgfem_main<<<dim3(HW / TW, HW / TH, 32), dim3(256), 0, stream>>>(
        x0, kernArr, conv_w, conv_b, outp);
}

// Round 3
// 122.654 us; speedup vs baseline: 2.3858x; 2.3858x over previous
//
#include <hip/hip_runtime.h>

#define HW 128
#define TW 32
#define TH 8

__device__ __forceinline__ float lrelu(float x) { return x > 0.f ? x : 0.1f * x; }

// Static device scratch (ws has exactly 73728 B = kernArr, no spare room).
__device__ float g_kern[32 * 64 * 9];   // att-folded depthwise kernels
__device__ float g_wT[64 * 64];         // g_wT[c*64+o] = conv_w[o*64+c]

// ---------------- prep: b<32 -> att-scaled kernels; b==32 -> W transpose ----------------
__global__ __launch_bounds__(64) void dgfem_prep(
    const float* __restrict__ v, const float* __restrict__ ca_w1,
    const float* __restrict__ ca_w2, const float* __restrict__ k_w1,
    const float* __restrict__ k_w2, const float* __restrict__ conv_w)
{
    const int b = blockIdx.x;
    const int t = threadIdx.x;           // 64 threads

    if (b == 32) {                       // transpose conv_w -> c-major rows
        for (int i = t; i < 4096; i += 64)
            g_wT[(i & 63) * 64 + (i >> 6)] = conv_w[i];
        return;
    }

    __shared__ float vb[64], t1[8], att[64], t2[64];
    vb[t] = v[b * 64 + t];
    __syncthreads();

    if (t < 8) {
        float s = 0.f;
        for (int j = 0; j < 64; ++j) s += vb[j] * ca_w1[t * 64 + j];
        t1[t] = lrelu(s);
    }
    {
        float s = 0.f;
        for (int j = 0; j < 64; ++j) s += vb[j] * k_w1[t * 64 + j];
        t2[t] = lrelu(s);
    }
    __syncthreads();
    {
        float s = 0.f;
        for (int i = 0; i < 8; ++i) s += t1[i] * ca_w2[t * 8 + i];
        att[t] = 1.f / (1.f + expf(-s));
    }
    __syncthreads();
    // fold att[c] into the kernel: conv(x*a, k) == conv(x, a*k)
    for (int r = t; r < 576; r += 64) {
        float s = 0.f;
        for (int j = 0; j < 64; ++j) s += t2[j] * k_w2[r * 64 + j];
        g_kern[b * 576 + r] = s * att[r / 9];
    }
}

// ---- fused: depthwise 3x3 (direct from global/L1) + lrelu + 1x1 via SGPR W ----
__global__ __launch_bounds__(256) void dgfem_main(
    const float* __restrict__ x0, const float* __restrict__ conv_b,
    float* __restrict__ out)
{
    const int t  = threadIdx.x;          // 256 = 32x8 pixel tile, 1 px/thread
    const int b  = blockIdx.z;
    const int gx = blockIdx.x * TW + (t & (TW - 1));
    const int gy = blockIdx.y * TH + (t >> 5);

    // per-thread stencil geometry: 9 offsets + 9 lane-mask bools (channel-invariant)
    int  off[9];
    bool msk[9];
    #pragma unroll
    for (int dy = 0; dy < 3; ++dy)
        #pragma unroll
        for (int dx = 0; dx < 3; ++dx) {
            int xi = gx + dx - 1, yi = gy + dy - 1;
            bool in = ((unsigned)xi < HW) && ((unsigned)yi < HW);
            off[dy * 3 + dx] = in ? (yi * HW + xi) : 0;
            msk[dy * 3 + dx] = in;
        }

    const size_t bbase = (size_t)b * 64 * (HW * HW);
    const float* xb = x0 + bbase;
    const float* kb = g_kern + b * 576;

    float acc[64];
    #pragma unroll
    for (int o = 0; o < 64; ++o) acc[o] = 0.f;

    #pragma unroll 2
    for (int c = 0; c < 64; ++c) {
        const float* xc = xb + c * (HW * HW);   // divergent offsets, uniform base
        const float* kc = kb + c * 9;           // uniform -> s_load
        const float* wc = g_wT + c * 64;        // uniform -> s_load

        float xv[9];
        #pragma unroll
        for (int tp = 0; tp < 9; ++tp) xv[tp] = xc[off[tp]];

        float yv = 0.f;
        #pragma unroll
        for (int tp = 0; tp < 9; ++tp) {
            float xm = msk[tp] ? xv[tp] : 0.f;  // zero-pad boundary
            yv += kc[tp] * xm;
        }
        yv = lrelu(yv);

        #pragma unroll
        for (int o = 0; o < 64; ++o)            // v_fma with SGPR weight
            acc[o] += wc[o] * yv;
    }

    float* op = out + bbase + (size_t)(gy * HW + gx);
    #pragma unroll
    for (int o = 0; o < 64; ++o)
        op[(size_t)o * (HW * HW)] = acc[o] + conv_b[o];
}

extern "C" void kernel_launch(void* const* d_in, const int* in_sizes, int n_in,
                              void* d_out, int out_size, void* d_ws, size_t ws_size,
                              hipStream_t stream) {
    const float* x0     = (const float*)d_in[0];
    const float* v      = (const float*)d_in[1];
    const float* ca_w1  = (const float*)d_in[2];
    const float* ca_w2  = (const float*)d_in[3];
    const float* k_w1   = (const float*)d_in[4];
    const float* k_w2   = (const float*)d_in[5];
    const float* conv_w = (const float*)d_in[6];
    const float* conv_b = (const float*)d_in[7];
    float* outp = (float*)d_out;

    dgfem_prep<<<dim3(33), dim3(64), 0, stream>>>(v, ca_w1, ca_w2, k_w1, k_w2, conv_w);
    dgfem_main<<<dim3(HW / TW, HW / TH, 32), dim3(256), 0, stream>>>(x0, conv_b, outp);
}